// Round 8
// baseline (17185.794 us; speedup 1.0000x reference)
//
#include <hip/hip_runtime.h>

// ---------------------------------------------------------------------------
// 2-layer LSTM LM forward, MI355X persistent-kernel design, round 8.
//
//   R7 skeleton (1-wave layer-0 critical path, zero barriers in loop) +
//   8x MIRRORED rings: publishers store their 16B to 8 mirror copies;
//   each consumer polls only mirror (bid & 7). Cuts per-L3-line readership
//   256 -> 32 and spreads the poll flood over 8x the banks/channels.
//
//   round r: layer0 computes step r (x_r = emb[tok[r-1]]), publishes tag r;
//            layer1 computes step r-1 from h0(r-1), h1(r-2), publishes r-1.
//   h travels as TAG-EMBEDDED u64 ((round<<32)|bf16x2), RELAXED agent
//   atomics. 2-deep parity ring per mirror; slot-1 invalidated at reset
//   (cross-replay stale-tag fix). Safety: any publisher's round-r overwrite
//   transitively requires all blocks' round-(r-1) polls complete (program
//   order in wave0) -- mirror-independent, same chain as R3-R7.
// ---------------------------------------------------------------------------

#define T_SEQ 4096
#define HID   1024
#define EMBD  512
#define VOCAB 50257
#define NBLK  256
#define TPB   256
#define UB    4
#define NMIR  8

// workspace layout (32-bit word offsets)
#define WS_H0T 0       // u64[8 mir][2 par][512]: (tag<<32)|bf16pair  (16384 u32)
#define WS_H1T 16384   // u64[8][2][512]
#define WS_H1F 32768   // float[1024] final h1
#define WS_LOG 33792   // float[50257] logits
#define WS_LSE 84049   // float[1]

// LDS layout (bytes)
#define OFF_W0 0                   // short8[48*64] = 49152
#define OFF_W1 49152               // short8[64*64] = 65536
#define OFF_V0 114688              // 2 x 768 u32  (x(256w) || h0(512w))
#define OFF_V1 120832              // 2 x 512 u32  (h1)
#define OFF_PP 124928              // float[2][16] layer1 partials
#define OFF_FL 125056              // unsigned[8] flags
#define SMEM_BYTES 125088

// flag indices
#define FL_SF0 0   // wave0: v0[r&1] staged for round r
#define FL_SF1 1   // wave1: v1[r&1] staged for round r
#define FL_PA1 2   // wave2: layer1 partial A done round r (also: v0 reads done)
#define FL_C3  3   // wave3: v1 reads done round r

typedef __attribute__((ext_vector_type(8))) short short8;
typedef __attribute__((ext_vector_type(4))) float f32x4;
typedef unsigned long long u64;

__device__ __forceinline__ unsigned short f2bf(float f) {
  unsigned int u = __float_as_uint(f);
  u += 0x7FFFu + ((u >> 16) & 1u);          // round-to-nearest-even
  return (unsigned short)(u >> 16);
}
__device__ __forceinline__ unsigned int pack2bf(float a, float b) {
  return (unsigned int)f2bf(a) | ((unsigned int)f2bf(b) << 16);
}
__device__ __forceinline__ float sigmoidf_(float x) {
  return 1.f / (1.f + __expf(-x));
}
__device__ __forceinline__ float tanhf_(float x) {
  return 1.f - 2.f / (__expf(2.f * x) + 1.f);
}
__device__ __forceinline__ unsigned ldsacq(const unsigned* p) {
  return __hip_atomic_load(p, __ATOMIC_ACQUIRE, __HIP_MEMORY_SCOPE_WORKGROUP);
}
__device__ __forceinline__ void ldsrel(unsigned* p, unsigned v) {
  __hip_atomic_store(p, v, __ATOMIC_RELEASE, __HIP_MEMORY_SCOPE_WORKGROUP);
}
__device__ __forceinline__ u64 agld(const u64* p) {
  return __hip_atomic_load(p, __ATOMIC_RELAXED, __HIP_MEMORY_SCOPE_AGENT);
}
__device__ __forceinline__ void agst(u64* p, u64 v) {
  __hip_atomic_store(p, v, __ATOMIC_RELAXED, __HIP_MEMORY_SCOPE_AGENT);
}

// NS MFMA k-segments; A = v broadcast from LDS, B = weight frags from LDS
// (1KB/wave contiguous, conflict-free). Any lane->k map cancels between
// A and B. D: col = lane&15 = gate-row (HW-verified C/D layout).
template<int NS>
__device__ __forceinline__ f32x4 mm_lds(const short8* vf, const short8* wf,
                                        int grp, int lane) {
  f32x4 a0 = {0.f, 0.f, 0.f, 0.f};
  f32x4 a1 = a0, a2 = a0, a3 = a0;
#pragma unroll
  for (int i = 0; i < NS; ++i) {
    short8 av = vf[i * 4 + grp];
    short8 bv = wf[i * 64 + lane];
    if ((i & 3) == 0)      a0 = __builtin_amdgcn_mfma_f32_16x16x32_bf16(av, bv, a0, 0, 0, 0);
    else if ((i & 3) == 1) a1 = __builtin_amdgcn_mfma_f32_16x16x32_bf16(av, bv, a1, 0, 0, 0);
    else if ((i & 3) == 2) a2 = __builtin_amdgcn_mfma_f32_16x16x32_bf16(av, bv, a2, 0, 0, 0);
    else                   a3 = __builtin_amdgcn_mfma_f32_16x16x32_bf16(av, bv, a3, 0, 0, 0);
  }
  return (a0 + a1) + (a2 + a3);
}

// ---------------------------------------------------------------------------
__global__ __launch_bounds__(512, 1) void reset_kernel(
    const float* __restrict__ h0in, unsigned int* __restrict__ ws) {
  const int tid = threadIdx.x;
  u64* H0T = reinterpret_cast<u64*>(ws + WS_H0T);
  u64* H1T = reinterpret_cast<u64*>(ws + WS_H1T);
  const u64 w0 = (u64)pack2bf(h0in[2 * tid], h0in[2 * tid + 1]);
  const u64 w1 = (u64)pack2bf(h0in[HID + 2 * tid], h0in[HID + 2 * tid + 1]);
#pragma unroll
  for (int m = 0; m < NMIR; ++m) {
    agst(&H0T[m * 1024 + tid], w0);                       // slot 0: tag 0
    agst(&H0T[m * 1024 + 512 + tid], 0xFFFFFFFF00000000ULL);  // slot 1: INVALID
    agst(&H1T[m * 1024 + tid], w1);
    agst(&H1T[m * 1024 + 512 + tid], 0xFFFFFFFF00000000ULL);
  }
}

// ---------------------------------------------------------------------------
__global__ __launch_bounds__(TPB, 1) void scan_kernel(
    const int* __restrict__ tok,
    const float* __restrict__ h0in, const float* __restrict__ c0in,
    const float* __restrict__ emb,
    const float* __restrict__ wih0, const float* __restrict__ whh0,
    const float* __restrict__ bih0, const float* __restrict__ bhh0,
    const float* __restrict__ wih1, const float* __restrict__ whh1,
    const float* __restrict__ bih1, const float* __restrict__ bhh1,
    float* __restrict__ dout, unsigned int* __restrict__ ws) {
  extern __shared__ char smem[];
  short8* W0f = reinterpret_cast<short8*>(smem + OFF_W0);
  short8* W1f = reinterpret_cast<short8*>(smem + OFF_W1);
  unsigned int* v0w = reinterpret_cast<unsigned int*>(smem + OFF_V0);
  unsigned int* v1w = reinterpret_cast<unsigned int*>(smem + OFF_V1);
  const short8* v0f = reinterpret_cast<const short8*>(smem + OFF_V0);
  const short8* v1f = reinterpret_cast<const short8*>(smem + OFF_V1);
  float* pp  = reinterpret_cast<float*>(smem + OFF_PP);
  unsigned* flg = reinterpret_cast<unsigned*>(smem + OFF_FL);

  const int tid = threadIdx.x;
  const int bid = blockIdx.x;
  const int lane = tid & 63;
  const int w = tid >> 6;
  const int grp = lane >> 4;
  const int mymir = bid & 7;

  // ---- stage weights into LDS as pre-swizzled B-fragments (bf16) ----
  for (int slot = tid; slot < 48 * 64; slot += TPB) {
    const int seg = slot >> 6, l = slot & 63;
    const int col = l & 15, g = l >> 4;
    const int grow = (col >> 2) * HID + bid * UB + (col & 3);
    const int k0 = seg * 32 + g * 8;
    const float* src = (k0 < EMBD) ? (wih0 + (size_t)grow * EMBD + k0)
                                   : (whh0 + (size_t)grow * HID + (k0 - EMBD));
    const float4* s4 = reinterpret_cast<const float4*>(src);
    float4 f0 = s4[0], f1 = s4[1];
    short8 pk;
    pk[0] = (short)f2bf(f0.x); pk[1] = (short)f2bf(f0.y);
    pk[2] = (short)f2bf(f0.z); pk[3] = (short)f2bf(f0.w);
    pk[4] = (short)f2bf(f1.x); pk[5] = (short)f2bf(f1.y);
    pk[6] = (short)f2bf(f1.z); pk[7] = (short)f2bf(f1.w);
    W0f[slot] = pk;
  }
  for (int slot = tid; slot < 64 * 64; slot += TPB) {
    const int seg = slot >> 6, l = slot & 63;
    const int col = l & 15, g = l >> 4;
    const int grow = (col >> 2) * HID + bid * UB + (col & 3);
    const int k0 = seg * 32 + g * 8;
    const float* src = (k0 < HID) ? (wih1 + (size_t)grow * HID + k0)
                                  : (whh1 + (size_t)grow * HID + (k0 - HID));
    const float4* s4 = reinterpret_cast<const float4*>(src);
    float4 f0 = s4[0], f1 = s4[1];
    short8 pk;
    pk[0] = (short)f2bf(f0.x); pk[1] = (short)f2bf(f0.y);
    pk[2] = (short)f2bf(f0.z); pk[3] = (short)f2bf(f0.w);
    pk[4] = (short)f2bf(f1.x); pk[5] = (short)f2bf(f1.y);
    pk[6] = (short)f2bf(f1.z); pk[7] = (short)f2bf(f1.w);
    W1f[slot] = pk;
  }
  if (tid < 8) flg[tid] = 1u;   // "rounds <= 1 complete" for lag-2 gates

  u64* H0T = reinterpret_cast<u64*>(ws + WS_H0T);
  u64* H1T = reinterpret_cast<u64*>(ws + WS_H1T);

  __syncthreads();   // weights + flags ready; the last barrier in the kernel

  if (w == 0) {
    // ============ wave 0: the ENTIRE layer-0 recurrence =====================
    float bs0 = 0.f;
    if (lane < 16) {
      const int grow = (lane >> 2) * HID + bid * UB + (lane & 3);
      bs0 = bih0[grow] + bhh0[grow];
    }
    float cst = (lane < UB) ? c0in[bid * UB + lane] : 0.f;

    const float4* e4 = reinterpret_cast<const float4*>(emb) + (size_t)tok[0] * 128;
    float4 xA = e4[lane], xB = e4[64 + lane];

    for (int r = 1; r <= T_SEQ + 1; ++r) {
      const int p = r & 1;
      if (r >= 3) {
        const unsigned need = (unsigned)(r - 2);
        while (ldsacq(&flg[FL_PA1]) < need) { }
      }
      if (r <= T_SEQ) {
        u64* vx = reinterpret_cast<u64*>(v0w + p * 768);
        vx[lane]      = (u64)pack2bf(xA.x, xA.y) | ((u64)pack2bf(xA.z, xA.w) << 32);
        vx[64 + lane] = (u64)pack2bf(xB.x, xB.y) | ((u64)pack2bf(xB.z, xB.w) << 32);
        if (r <= T_SEQ - 1) {
          const float4* en = reinterpret_cast<const float4*>(emb) + (size_t)tok[r] * 128;
          xA = en[lane]; xB = en[64 + lane];
        }
      }
      // poll h0(r-1) from THIS block's mirror: 8 tagged u64 per lane
      {
        const unsigned tg = (unsigned)(r - 1);
        const u64* ap = &H0T[mymir * 1024 + ((r - 1) & 1) * 512 + lane];
        u64 d0 = 0, d1 = 0, d2 = 0, d3 = 0, d4 = 0, d5 = 0, d6 = 0, d7 = 0;
        bool k0 = false, k1 = false, k2 = false, k3 = false;
        bool k4 = false, k5 = false, k6 = false, k7 = false;
        for (;;) {
          if (!k0) { d0 = agld(ap);       k0 = ((unsigned)(d0 >> 32) == tg); }
          if (!k1) { d1 = agld(ap + 64);  k1 = ((unsigned)(d1 >> 32) == tg); }
          if (!k2) { d2 = agld(ap + 128); k2 = ((unsigned)(d2 >> 32) == tg); }
          if (!k3) { d3 = agld(ap + 192); k3 = ((unsigned)(d3 >> 32) == tg); }
          if (!k4) { d4 = agld(ap + 256); k4 = ((unsigned)(d4 >> 32) == tg); }
          if (!k5) { d5 = agld(ap + 320); k5 = ((unsigned)(d5 >> 32) == tg); }
          if (!k6) { d6 = agld(ap + 384); k6 = ((unsigned)(d6 >> 32) == tg); }
          if (!k7) { d7 = agld(ap + 448); k7 = ((unsigned)(d7 >> 32) == tg); }
          if (k0 && k1 && k2 && k3 && k4 && k5 && k6 && k7) break;
        }
        unsigned* dst = v0w + p * 768 + 256 + lane;
        dst[0] = (unsigned)d0;   dst[64] = (unsigned)d1;
        dst[128] = (unsigned)d2; dst[192] = (unsigned)d3;
        dst[256] = (unsigned)d4; dst[320] = (unsigned)d5;
        dst[384] = (unsigned)d6; dst[448] = (unsigned)d7;
      }
      ldsrel(&flg[FL_SF0], (unsigned)r);   // layer1 (wave2) may start

      if (r <= T_SEQ) {
        f32x4 s = mm_lds<48>(v0f + p * 192, W0f, grp, lane);
        float g = (lane < 16) ? (s[0] + bs0) : 0.f;
        const int u = lane & 3;
        const float gi = __shfl(g, u),      gf = __shfl(g, 4 + u);
        const float gg = __shfl(g, 8 + u),  go = __shfl(g, 12 + u);
        float hv = 0.f;
        if (lane < UB) {
          const float c = sigmoidf_(gf) * cst + sigmoidf_(gi) * tanhf_(gg);
          cst = c;
          hv = sigmoidf_(go) * tanhf_(c);
          if (r == T_SEQ) {
            dout[VOCAB + bid * UB + lane] = hv;             // h_n layer0
            dout[VOCAB + 2 * HID + bid * UB + lane] = c;    // c_n layer0
          }
        }
        // publish to ALL 8 mirrors: lanes 0-15, mirror = lane>>1, word = lane&1
        const float a = __shfl(hv, 2 * (lane & 1));
        const float b = __shfl(hv, 2 * (lane & 1) + 1);
        if (lane < 16)
          agst(&H0T[(lane >> 1) * 1024 + (r & 1) * 512 + bid * 2 + (lane & 1)],
               ((u64)(unsigned)r << 32) | (u64)pack2bf(a, b));
      }
      // r == T_SEQ+1: stage-only (feeds layer1's final step), no publish
    }
  } else if (w == 1) {
    // ============ wave 1: h1 ring poller (own mirror) =======================
    for (int r = 2; r <= T_SEQ + 1; ++r) {
      const int p = r & 1;
      if (r >= 4) {
        const unsigned need = (unsigned)(r - 2);
        while (ldsacq(&flg[FL_C3]) < need) { }
      }
      const unsigned tg = (unsigned)(r - 2);
      const u64* ap = &H1T[mymir * 1024 + p * 512 + lane];   // (r-2)&1 == r&1
      u64 d0 = 0, d1 = 0, d2 = 0, d3 = 0, d4 = 0, d5 = 0, d6 = 0, d7 = 0;
      bool k0 = false, k1 = false, k2 = false, k3 = false;
      bool k4 = false, k5 = false, k6 = false, k7 = false;
      for (;;) {
        if (!k0) { d0 = agld(ap);       k0 = ((unsigned)(d0 >> 32) == tg); }
        if (!k1) { d1 = agld(ap + 64);  k1 = ((unsigned)(d1 >> 32) == tg); }
        if (!k2) { d2 = agld(ap + 128); k2 = ((unsigned)(d2 >> 32) == tg); }
        if (!k3) { d3 = agld(ap + 192); k3 = ((unsigned)(d3 >> 32) == tg); }
        if (!k4) { d4 = agld(ap + 256); k4 = ((unsigned)(d4 >> 32) == tg); }
        if (!k5) { d5 = agld(ap + 320); k5 = ((unsigned)(d5 >> 32) == tg); }
        if (!k6) { d6 = agld(ap + 384); k6 = ((unsigned)(d6 >> 32) == tg); }
        if (!k7) { d7 = agld(ap + 448); k7 = ((unsigned)(d7 >> 32) == tg); }
        if (k0 && k1 && k2 && k3 && k4 && k5 && k6 && k7) break;
      }
      unsigned* dst = v1w + p * 512 + lane;
      dst[0] = (unsigned)d0;   dst[64] = (unsigned)d1;
      dst[128] = (unsigned)d2; dst[192] = (unsigned)d3;
      dst[256] = (unsigned)d4; dst[320] = (unsigned)d5;
      dst[384] = (unsigned)d6; dst[448] = (unsigned)d7;
      ldsrel(&flg[FL_SF1], (unsigned)r);
    }
  } else if (w == 2) {
    // ============ wave 2: layer-1 partial A (h0 half, reads v0) =============
    for (int r = 2; r <= T_SEQ + 1; ++r) {
      const int p = r & 1;
      const unsigned ru = (unsigned)r;
      while (ldsacq(&flg[FL_SF0]) < ru) { }
      f32x4 s = mm_lds<32>(v0f + p * 192 + 64, W1f, grp, lane);
      if (lane < 16) pp[p * 16 + lane] = s[0];
      ldsrel(&flg[FL_PA1], ru);     // partial ready AND v0[p] reads done
    }
  } else {
    // ============ wave 3: layer-1 partial B (h1 half) + gates + publish =====
    float bs1 = 0.f;
    if (lane < 16) {
      const int grow = (lane >> 2) * HID + bid * UB + (lane & 3);
      bs1 = bih1[grow] + bhh1[grow];
    }
    float cst = (lane < UB) ? c0in[HID + bid * UB + lane] : 0.f;
    for (int r = 2; r <= T_SEQ + 1; ++r) {
      const int p = r & 1;
      const unsigned ru = (unsigned)r;
      while (ldsacq(&flg[FL_SF1]) < ru) { }
      f32x4 s = mm_lds<32>(v1f + p * 128, W1f + 32 * 64, grp, lane);
      ldsrel(&flg[FL_C3], ru);                 // v1[p] reads done
      while (ldsacq(&flg[FL_PA1]) < ru) { }
      float g = (lane < 16) ? (s[0] + pp[p * 16 + lane] + bs1) : 0.f;
      const int u = lane & 3;
      const float gi = __shfl(g, u),      gf = __shfl(g, 4 + u);
      const float gg = __shfl(g, 8 + u),  go = __shfl(g, 12 + u);
      float hv = 0.f;
      if (lane < UB) {
        const float c = sigmoidf_(gf) * cst + sigmoidf_(gi) * tanhf_(gg);
        cst = c;
        hv = sigmoidf_(go) * tanhf_(c);
        if (r == T_SEQ + 1) {
          float* h1f = reinterpret_cast<float*>(ws + WS_H1F);
          h1f[bid * UB + lane] = hv;
          dout[VOCAB + HID + bid * UB + lane] = hv;          // h_n layer1
          dout[VOCAB + 3 * HID + bid * UB + lane] = c;       // c_n layer1
        }
      }
      const float a = __shfl(hv, 2 * (lane & 1));
      const float b = __shfl(hv, 2 * (lane & 1) + 1);
      if (lane < 16)
        agst(&H1T[(lane >> 1) * 1024 + ((r - 1) & 1) * 512 + bid * 2 + (lane & 1)],
             ((u64)(unsigned)(r - 1) << 32) | (u64)pack2bf(a, b));
    }
  }
}

// ---------------------------------------------------------------------------
__global__ __launch_bounds__(256) void logits_kernel(
    const float* __restrict__ wout, const float* __restrict__ bout,
    unsigned int* __restrict__ ws) {
  const float* h1f = reinterpret_cast<const float*>(ws + WS_H1F);
  float* lg = reinterpret_cast<float*>(ws + WS_LOG);
  const int lane = threadIdx.x & 63;
  const int wv = threadIdx.x >> 6;
  const int gw = blockIdx.x * 4 + wv;    // 1024 waves total
  const float4* h4 = reinterpret_cast<const float4*>(h1f);
  float4 h[4];
#pragma unroll
  for (int j = 0; j < 4; ++j) h[j] = h4[j * 64 + lane];
  for (int v = gw; v < VOCAB; v += 1024) {
    const float4* wr = reinterpret_cast<const float4*>(wout + (size_t)v * HID);
    float s = 0.f;
#pragma unroll
    for (int j = 0; j < 4; ++j) {
      float4 x = wr[j * 64 + lane];
      s += x.x * h[j].x + x.y * h[j].y + x.z * h[j].z + x.w * h[j].w;
    }
#pragma unroll
    for (int m = 32; m >= 1; m >>= 1) s += __shfl_xor(s, m, 64);
    if (lane == 0) lg[v] = s + bout[v];
  }
}

__global__ __launch_bounds__(1024) void lse_kernel(unsigned int* __restrict__ ws) {
  const float* lg = reinterpret_cast<const float*>(ws + WS_LOG);
  __shared__ float wred[16];
  __shared__ float mshare;
  const int tid = threadIdx.x;
  float m = -3.4e38f;
  for (int i = tid; i < VOCAB; i += 1024) m = fmaxf(m, lg[i]);
#pragma unroll
  for (int s = 32; s >= 1; s >>= 1) m = fmaxf(m, __shfl_xor(m, s, 64));
  if ((tid & 63) == 0) wred[tid >> 6] = m;
  __syncthreads();
  if (tid == 0) {
    float mm = wred[0];
    for (int i = 1; i < 16; ++i) mm = fmaxf(mm, wred[i]);
    mshare = mm;
  }
  __syncthreads();
  const float M = mshare;
  float a = 0.f;
  for (int i = tid; i < VOCAB; i += 1024) a += __expf(lg[i] - M);
#pragma unroll
  for (int s = 32; s >= 1; s >>= 1) a += __shfl_xor(a, s, 64);
  __syncthreads();
  if ((tid & 63) == 0) wred[tid >> 6] = a;
  __syncthreads();
  if (tid == 0) {
    float ss = 0.f;
    for (int i = 0; i < 16; ++i) ss += wred[i];
    reinterpret_cast<float*>(ws + WS_LSE)[0] = M + logf(ss);
  }
}

__global__ __launch_bounds__(256) void out_kernel(
    const unsigned int* __restrict__ ws, float* __restrict__ dout) {
  const float lse = reinterpret_cast<const float*>(ws + WS_LSE)[0];
  const float* lg = reinterpret_cast<const float*>(ws + WS_LOG);
  const int i = blockIdx.x * 256 + threadIdx.x;
  if (i < VOCAB) dout[i] = lg[i] - lse;
}

// ---------------------------------------------------------------------------
extern "C" void kernel_launch(void* const* d_in, const int* in_sizes, int n_in,
                              void* d_out, int out_size, void* d_ws, size_t ws_size,
                              hipStream_t stream) {
  const int*   tok  = (const int*)d_in[0];
  const float* h0in = (const float*)d_in[1];
  const float* c0in = (const float*)d_in[2];
  const float* emb  = (const float*)d_in[3];
  const float* wih0 = (const float*)d_in[4];
  const float* whh0 = (const float*)d_in[5];
  const float* bih0 = (const float*)d_in[6];
  const float* bhh0 = (const float*)d_in[7];
  const float* wih1 = (const float*)d_in[8];
  const float* whh1 = (const float*)d_in[9];
  const float* bih1 = (const float*)d_in[10];
  const float* bhh1 = (const float*)d_in[11];
  const float* wout = (const float*)d_in[12];
  const float* bout = (const float*)d_in[13];
  float* out = (float*)d_out;
  unsigned int* ws = (unsigned int*)d_ws;

  (void)in_sizes; (void)n_in; (void)out_size; (void)ws_size;

  (void)hipFuncSetAttribute((const void*)scan_kernel,
                            hipFuncAttributeMaxDynamicSharedMemorySize, SMEM_BYTES);

  reset_kernel<<<1, 512, 0, stream>>>(h0in, ws);
  scan_kernel<<<NBLK, TPB, SMEM_BYTES, stream>>>(
      tok, h0in, c0in, emb, wih0, whh0, bih0, bhh0,
      wih1, whh1, bih1, bhh1, out, ws);
  logits_kernel<<<256, 256, 0, stream>>>(wout, bout, ws);
  lse_kernel<<<1, 1024, 0, stream>>>(ws);
  out_kernel<<<(VOCAB + 255) / 256, 256, 0, stream>>>(ws, out);
}

// Round 9
// 15353.778 us; speedup vs baseline: 1.1193x; 1.1193x over previous
//
#include <hip/hip_runtime.h>

// ---------------------------------------------------------------------------
// 2-layer LSTM LM forward, MI355X persistent-kernel design, round 9.
//
//   R7 skeleton (1-wave layer-0 critical path, zero barriers in loop, plain
//   single ring, tag-embedded u64, RELAXED agent atomics) + two latency
//   overlaps:
//     (a) x-part of layer-0 matvec (segs 0-15) runs BEFORE the h0 poll
//         (no dependence on incoming h0) -> shorter post-detect chain;
//     (b) h0 poll split: wave0 polls ring words 0-255 (4/lane), wave1 polls
//         words 256-511 concurrently; wave0 consumes wave1's half only for
//         the last 16 segs, so the waits overlap mm work.
//
//   round r: layer0 computes step r (x_r = emb[tok[r-1]]), publishes tag r;
//            layer1 computes step r-1 from h0(r-1), h1(r-2), publishes r-1.
//   Safety: identical happens-before chain as R3-R7 (publish(r) transitively
//   requires all blocks' round-(r-1) polls complete). v0 overwrite gates:
//   each staging half checks FL_PA1 >= r-2 (wave2 done reading that parity).
// ---------------------------------------------------------------------------

#define T_SEQ 4096
#define HID   1024
#define EMBD  512
#define VOCAB 50257
#define NBLK  256
#define TPB   256
#define UB    4

// workspace layout (32-bit word offsets)
#define WS_H0T 0       // u64[2][512]: (tag<<32)|bf16pair
#define WS_H1T 2048    // u64[2][512]
#define WS_H1F 4096    // float[1024] final h1
#define WS_LOG 5120    // float[50257] logits
#define WS_LSE 55377   // float[1]

// LDS layout (bytes)
#define OFF_W0 0                   // short8[48*64] = 49152
#define OFF_W1 49152               // short8[64*64] = 65536
#define OFF_V0 114688              // 2 x 768 u32  (x(256w) || h0(512w))
#define OFF_V1 120832              // 2 x 512 u32  (h1)
#define OFF_PP 124928              // float[2][16] layer1 partials
#define OFF_FL 125056              // unsigned[8] flags
#define SMEM_BYTES 125088

// flag indices
#define FL_SF0A 0  // wave0: v0[r&1] lower h0 half staged for round r
#define FL_SF0B 1  // wave1: v0[r&1] upper h0 half staged for round r
#define FL_SF1  2  // wave1: v1[r&1] staged for round r
#define FL_PA1  3  // wave2: layer1 partial A done round r (v0 reads done)
#define FL_C3   4  // wave3: v1 reads done round r

typedef __attribute__((ext_vector_type(8))) short short8;
typedef __attribute__((ext_vector_type(4))) float f32x4;
typedef unsigned long long u64;

__device__ __forceinline__ unsigned short f2bf(float f) {
  unsigned int u = __float_as_uint(f);
  u += 0x7FFFu + ((u >> 16) & 1u);          // round-to-nearest-even
  return (unsigned short)(u >> 16);
}
__device__ __forceinline__ unsigned int pack2bf(float a, float b) {
  return (unsigned int)f2bf(a) | ((unsigned int)f2bf(b) << 16);
}
__device__ __forceinline__ float sigmoidf_(float x) {
  return 1.f / (1.f + __expf(-x));
}
__device__ __forceinline__ float tanhf_(float x) {
  return 1.f - 2.f / (__expf(2.f * x) + 1.f);
}
__device__ __forceinline__ unsigned ldsacq(const unsigned* p) {
  return __hip_atomic_load(p, __ATOMIC_ACQUIRE, __HIP_MEMORY_SCOPE_WORKGROUP);
}
__device__ __forceinline__ void ldsrel(unsigned* p, unsigned v) {
  __hip_atomic_store(p, v, __ATOMIC_RELEASE, __HIP_MEMORY_SCOPE_WORKGROUP);
}
__device__ __forceinline__ u64 agld(const u64* p) {
  return __hip_atomic_load(p, __ATOMIC_RELAXED, __HIP_MEMORY_SCOPE_AGENT);
}
__device__ __forceinline__ void agst(u64* p, u64 v) {
  __hip_atomic_store(p, v, __ATOMIC_RELAXED, __HIP_MEMORY_SCOPE_AGENT);
}

// NS MFMA k-segments ACCUMULATED into acc[4]; A = v broadcast from LDS,
// B = weight frags from LDS (1KB/wave contiguous, conflict-free). Any
// lane->k map cancels between A and B. D: col = lane&15 = gate-row.
template<int NS>
__device__ __forceinline__ void mm_acc(f32x4 (&acc)[4], const short8* vf,
                                       const short8* wf, int grp, int lane) {
#pragma unroll
  for (int i = 0; i < NS; ++i) {
    short8 av = vf[i * 4 + grp];
    short8 bv = wf[i * 64 + lane];
    acc[i & 3] = __builtin_amdgcn_mfma_f32_16x16x32_bf16(av, bv, acc[i & 3], 0, 0, 0);
  }
}

// ---------------------------------------------------------------------------
__global__ __launch_bounds__(512, 1) void reset_kernel(
    const float* __restrict__ h0in, unsigned int* __restrict__ ws) {
  const int tid = threadIdx.x;
  u64* H0T = reinterpret_cast<u64*>(ws + WS_H0T);
  u64* H1T = reinterpret_cast<u64*>(ws + WS_H1T);
  // slot 0 <- initial hidden states tag 0; slot 1 <- INVALID tag (kills the
  // cross-replay stale-tag race). Agent-scope so the scan's polls see them.
  agst(&H0T[tid], (u64)pack2bf(h0in[2 * tid], h0in[2 * tid + 1]));
  agst(&H1T[tid], (u64)pack2bf(h0in[HID + 2 * tid], h0in[HID + 2 * tid + 1]));
  agst(&H0T[512 + tid], 0xFFFFFFFF00000000ULL);
  agst(&H1T[512 + tid], 0xFFFFFFFF00000000ULL);
}

// ---------------------------------------------------------------------------
__global__ __launch_bounds__(TPB, 1) void scan_kernel(
    const int* __restrict__ tok,
    const float* __restrict__ h0in, const float* __restrict__ c0in,
    const float* __restrict__ emb,
    const float* __restrict__ wih0, const float* __restrict__ whh0,
    const float* __restrict__ bih0, const float* __restrict__ bhh0,
    const float* __restrict__ wih1, const float* __restrict__ whh1,
    const float* __restrict__ bih1, const float* __restrict__ bhh1,
    float* __restrict__ dout, unsigned int* __restrict__ ws) {
  extern __shared__ char smem[];
  short8* W0f = reinterpret_cast<short8*>(smem + OFF_W0);
  short8* W1f = reinterpret_cast<short8*>(smem + OFF_W1);
  unsigned int* v0w = reinterpret_cast<unsigned int*>(smem + OFF_V0);
  unsigned int* v1w = reinterpret_cast<unsigned int*>(smem + OFF_V1);
  const short8* v0f = reinterpret_cast<const short8*>(smem + OFF_V0);
  const short8* v1f = reinterpret_cast<const short8*>(smem + OFF_V1);
  float* pp  = reinterpret_cast<float*>(smem + OFF_PP);
  unsigned* flg = reinterpret_cast<unsigned*>(smem + OFF_FL);

  const int tid = threadIdx.x;
  const int bid = blockIdx.x;
  const int lane = tid & 63;
  const int w = tid >> 6;
  const int grp = lane >> 4;

  // ---- stage weights into LDS as pre-swizzled B-fragments (bf16) ----
  for (int slot = tid; slot < 48 * 64; slot += TPB) {
    const int seg = slot >> 6, l = slot & 63;
    const int col = l & 15, g = l >> 4;
    const int grow = (col >> 2) * HID + bid * UB + (col & 3);
    const int k0 = seg * 32 + g * 8;
    const float* src = (k0 < EMBD) ? (wih0 + (size_t)grow * EMBD + k0)
                                   : (whh0 + (size_t)grow * HID + (k0 - EMBD));
    const float4* s4 = reinterpret_cast<const float4*>(src);
    float4 f0 = s4[0], f1 = s4[1];
    short8 pk;
    pk[0] = (short)f2bf(f0.x); pk[1] = (short)f2bf(f0.y);
    pk[2] = (short)f2bf(f0.z); pk[3] = (short)f2bf(f0.w);
    pk[4] = (short)f2bf(f1.x); pk[5] = (short)f2bf(f1.y);
    pk[6] = (short)f2bf(f1.z); pk[7] = (short)f2bf(f1.w);
    W0f[slot] = pk;
  }
  for (int slot = tid; slot < 64 * 64; slot += TPB) {
    const int seg = slot >> 6, l = slot & 63;
    const int col = l & 15, g = l >> 4;
    const int grow = (col >> 2) * HID + bid * UB + (col & 3);
    const int k0 = seg * 32 + g * 8;
    const float* src = (k0 < HID) ? (wih1 + (size_t)grow * HID + k0)
                                  : (whh1 + (size_t)grow * HID + (k0 - HID));
    const float4* s4 = reinterpret_cast<const float4*>(src);
    float4 f0 = s4[0], f1 = s4[1];
    short8 pk;
    pk[0] = (short)f2bf(f0.x); pk[1] = (short)f2bf(f0.y);
    pk[2] = (short)f2bf(f0.z); pk[3] = (short)f2bf(f0.w);
    pk[4] = (short)f2bf(f1.x); pk[5] = (short)f2bf(f1.y);
    pk[6] = (short)f2bf(f1.z); pk[7] = (short)f2bf(f1.w);
    W1f[slot] = pk;
  }
  if (tid < 8) flg[tid] = 1u;   // "rounds <= 1 complete" for lag gates

  u64* H0T = reinterpret_cast<u64*>(ws + WS_H0T);
  u64* H1T = reinterpret_cast<u64*>(ws + WS_H1T);

  __syncthreads();   // weights + flags ready; the last barrier in the kernel

  if (w == 0) {
    // ============ wave 0: layer-0 owner (x-mm early, lower h0 poll) =========
    float bs0 = 0.f;
    if (lane < 16) {
      const int grow = (lane >> 2) * HID + bid * UB + (lane & 3);
      bs0 = bih0[grow] + bhh0[grow];
    }
    float cst = (lane < UB) ? c0in[bid * UB + lane] : 0.f;

    const float4* e4 = reinterpret_cast<const float4*>(emb) + (size_t)tok[0] * 128;
    float4 xA = e4[lane], xB = e4[64 + lane];

    for (int r = 1; r <= T_SEQ + 1; ++r) {
      const int p = r & 1;
      f32x4 acc[4];
      acc[0] = f32x4{0.f, 0.f, 0.f, 0.f};
      acc[1] = acc[0]; acc[2] = acc[0]; acc[3] = acc[0];

      if (r <= T_SEQ) {
        // x_r into v0[p] words 0-255 (safe: only this wave read them, r-2)
        u64* vx = reinterpret_cast<u64*>(v0w + p * 768);
        vx[lane]      = (u64)pack2bf(xA.x, xA.y) | ((u64)pack2bf(xA.z, xA.w) << 32);
        vx[64 + lane] = (u64)pack2bf(xB.x, xB.y) | ((u64)pack2bf(xB.z, xB.w) << 32);
        // x-part matvec (segs 0-15) BEFORE the poll — no h0 dependence
        mm_acc<16>(acc, v0f + p * 192, W0f, grp, lane);
        // issue x_{r+1} prefetch (drains under the poll)
        if (r <= T_SEQ - 1) {
          const float4* en = reinterpret_cast<const float4*>(emb) + (size_t)tok[r] * 128;
          xA = en[lane]; xB = en[64 + lane];
        }
      }

      // overwrite gate for h0-lower staging (wave2 read v0[p] at round r-2)
      if (r >= 3) {
        const unsigned need = (unsigned)(r - 2);
        while (ldsacq(&flg[FL_PA1]) < need) { }
      }
      // poll h0(r-1) LOWER half: ring words 0-255, 4 tagged u64 per lane
      {
        const unsigned tg = (unsigned)(r - 1);
        const u64* ap = &H0T[((r - 1) & 1) * 512 + lane];
        u64 d0 = 0, d1 = 0, d2 = 0, d3 = 0;
        bool k0 = false, k1 = false, k2 = false, k3 = false;
        for (;;) {
          if (!k0) { d0 = agld(ap);       k0 = ((unsigned)(d0 >> 32) == tg); }
          if (!k1) { d1 = agld(ap + 64);  k1 = ((unsigned)(d1 >> 32) == tg); }
          if (!k2) { d2 = agld(ap + 128); k2 = ((unsigned)(d2 >> 32) == tg); }
          if (!k3) { d3 = agld(ap + 192); k3 = ((unsigned)(d3 >> 32) == tg); }
          if (k0 && k1 && k2 && k3) break;
        }
        unsigned* dst = v0w + p * 768 + 256 + lane;
        dst[0] = (unsigned)d0;   dst[64] = (unsigned)d1;
        dst[128] = (unsigned)d2; dst[192] = (unsigned)d3;
      }
      ldsrel(&flg[FL_SF0A], (unsigned)r);

      if (r <= T_SEQ) {
        // h0 lower half (segs 16-31) — wave1's half not needed yet
        mm_acc<16>(acc, v0f + p * 192 + 64, W0f + 16 * 64, grp, lane);
        // wait for wave1's upper half (usually long done), then segs 32-47
        {
          const unsigned ru = (unsigned)r;
          while (ldsacq(&flg[FL_SF0B]) < ru) { }
        }
        mm_acc<16>(acc, v0f + p * 192 + 128, W0f + 32 * 64, grp, lane);

        f32x4 s = (acc[0] + acc[1]) + (acc[2] + acc[3]);
        float g = (lane < 16) ? (s[0] + bs0) : 0.f;
        const int u = lane & 3;
        const float gi = __shfl(g, u),      gf = __shfl(g, 4 + u);
        const float gg = __shfl(g, 8 + u),  go = __shfl(g, 12 + u);
        float hv = 0.f;
        if (lane < UB) {
          const float c = sigmoidf_(gf) * cst + sigmoidf_(gi) * tanhf_(gg);
          cst = c;
          hv = sigmoidf_(go) * tanhf_(c);
        }
        const float a = __shfl(hv, 2 * (lane & 1));
        const float b = __shfl(hv, 2 * (lane & 1) + 1);
        if (lane < 2)
          agst(&H0T[(r & 1) * 512 + bid * 2 + lane],
               ((u64)(unsigned)r << 32) | (u64)pack2bf(a, b));
        if (r == T_SEQ && lane < UB) {
          dout[VOCAB + bid * UB + lane] = hv;             // h_n layer0
          dout[VOCAB + 2 * HID + bid * UB + lane] = cst;  // c_n layer0
        }
      }
      // r == T_SEQ+1: stage-only (feeds layer1's final step), no publish
    }
  } else if (w == 1) {
    // ============ wave 1: upper h0 poll, then h1 poll =======================
    for (int r = 1; r <= T_SEQ + 1; ++r) {
      const int p = r & 1;
      // overwrite gate for h0-upper staging (wave2 read v0[p] at round r-2)
      if (r >= 3) {
        const unsigned need = (unsigned)(r - 2);
        while (ldsacq(&flg[FL_PA1]) < need) { }
      }
      // poll h0(r-1) UPPER half: ring words 256-511, 4 tagged u64 per lane
      {
        const unsigned tg = (unsigned)(r - 1);
        const u64* ap = &H0T[((r - 1) & 1) * 512 + 256 + lane];
        u64 d0 = 0, d1 = 0, d2 = 0, d3 = 0;
        bool k0 = false, k1 = false, k2 = false, k3 = false;
        for (;;) {
          if (!k0) { d0 = agld(ap);       k0 = ((unsigned)(d0 >> 32) == tg); }
          if (!k1) { d1 = agld(ap + 64);  k1 = ((unsigned)(d1 >> 32) == tg); }
          if (!k2) { d2 = agld(ap + 128); k2 = ((unsigned)(d2 >> 32) == tg); }
          if (!k3) { d3 = agld(ap + 192); k3 = ((unsigned)(d3 >> 32) == tg); }
          if (k0 && k1 && k2 && k3) break;
        }
        unsigned* dst = v0w + p * 768 + 512 + lane;
        dst[0] = (unsigned)d0;   dst[64] = (unsigned)d1;
        dst[128] = (unsigned)d2; dst[192] = (unsigned)d3;
      }
      ldsrel(&flg[FL_SF0B], (unsigned)r);

      // h1 poll (slack path): v1[p] <- h1(r-2)
      if (r >= 2) {
        if (r >= 4) {                     // lag-2 gate: wave3 done with v1[p]
          const unsigned need = (unsigned)(r - 2);
          while (ldsacq(&flg[FL_C3]) < need) { }
        }
        const unsigned tg = (unsigned)(r - 2);
        const u64* ap = &H1T[p * 512 + lane];   // (r-2)&1 == r&1
        u64 d0 = 0, d1 = 0, d2 = 0, d3 = 0, d4 = 0, d5 = 0, d6 = 0, d7 = 0;
        bool k0 = false, k1 = false, k2 = false, k3 = false;
        bool k4 = false, k5 = false, k6 = false, k7 = false;
        for (;;) {
          if (!k0) { d0 = agld(ap);       k0 = ((unsigned)(d0 >> 32) == tg); }
          if (!k1) { d1 = agld(ap + 64);  k1 = ((unsigned)(d1 >> 32) == tg); }
          if (!k2) { d2 = agld(ap + 128); k2 = ((unsigned)(d2 >> 32) == tg); }
          if (!k3) { d3 = agld(ap + 192); k3 = ((unsigned)(d3 >> 32) == tg); }
          if (!k4) { d4 = agld(ap + 256); k4 = ((unsigned)(d4 >> 32) == tg); }
          if (!k5) { d5 = agld(ap + 320); k5 = ((unsigned)(d5 >> 32) == tg); }
          if (!k6) { d6 = agld(ap + 384); k6 = ((unsigned)(d6 >> 32) == tg); }
          if (!k7) { d7 = agld(ap + 448); k7 = ((unsigned)(d7 >> 32) == tg); }
          if (k0 && k1 && k2 && k3 && k4 && k5 && k6 && k7) break;
        }
        unsigned* dst = v1w + p * 512 + lane;
        dst[0] = (unsigned)d0;   dst[64] = (unsigned)d1;
        dst[128] = (unsigned)d2; dst[192] = (unsigned)d3;
        dst[256] = (unsigned)d4; dst[320] = (unsigned)d5;
        dst[384] = (unsigned)d6; dst[448] = (unsigned)d7;
        ldsrel(&flg[FL_SF1], (unsigned)r);
      }
    }
  } else if (w == 2) {
    // ============ wave 2: layer-1 partial A (h0 half, reads v0) =============
    for (int r = 2; r <= T_SEQ + 1; ++r) {
      const int p = r & 1;
      const unsigned ru = (unsigned)r;
      while (ldsacq(&flg[FL_SF0A]) < ru || ldsacq(&flg[FL_SF0B]) < ru) { }
      f32x4 acc[4];
      acc[0] = f32x4{0.f, 0.f, 0.f, 0.f};
      acc[1] = acc[0]; acc[2] = acc[0]; acc[3] = acc[0];
      mm_acc<32>(acc, v0f + p * 192 + 64, W1f, grp, lane);
      f32x4 s = (acc[0] + acc[1]) + (acc[2] + acc[3]);
      if (lane < 16) pp[p * 16 + lane] = s[0];
      ldsrel(&flg[FL_PA1], ru);     // partial ready AND v0[p] reads done
    }
  } else {
    // ============ wave 3: layer-1 partial B (h1 half) + gates + publish =====
    float bs1 = 0.f;
    if (lane < 16) {
      const int grow = (lane >> 2) * HID + bid * UB + (lane & 3);
      bs1 = bih1[grow] + bhh1[grow];
    }
    float cst = (lane < UB) ? c0in[HID + bid * UB + lane] : 0.f;
    for (int r = 2; r <= T_SEQ + 1; ++r) {
      const int p = r & 1;
      const unsigned ru = (unsigned)r;
      while (ldsacq(&flg[FL_SF1]) < ru) { }
      f32x4 acc[4];
      acc[0] = f32x4{0.f, 0.f, 0.f, 0.f};
      acc[1] = acc[0]; acc[2] = acc[0]; acc[3] = acc[0];
      mm_acc<32>(acc, v1f + p * 128, W1f + 32 * 64, grp, lane);
      f32x4 s = (acc[0] + acc[1]) + (acc[2] + acc[3]);
      ldsrel(&flg[FL_C3], ru);                 // v1[p] reads done
      while (ldsacq(&flg[FL_PA1]) < ru) { }
      float g = (lane < 16) ? (s[0] + pp[p * 16 + lane] + bs1) : 0.f;
      const int u = lane & 3;
      const float gi = __shfl(g, u),      gf = __shfl(g, 4 + u);
      const float gg = __shfl(g, 8 + u),  go = __shfl(g, 12 + u);
      float hv = 0.f;
      if (lane < UB) {
        const float c = sigmoidf_(gf) * cst + sigmoidf_(gi) * tanhf_(gg);
        cst = c;
        hv = sigmoidf_(go) * tanhf_(c);
        if (r == T_SEQ + 1) {
          float* h1f = reinterpret_cast<float*>(ws + WS_H1F);
          h1f[bid * UB + lane] = hv;
          dout[VOCAB + HID + bid * UB + lane] = hv;          // h_n layer1
          dout[VOCAB + 3 * HID + bid * UB + lane] = cst;     // c_n layer1
        }
      }
      const float a = __shfl(hv, 2 * (lane & 1));
      const float b = __shfl(hv, 2 * (lane & 1) + 1);
      if (lane < 2)
        agst(&H1T[((r - 1) & 1) * 512 + bid * 2 + lane],
             ((u64)(unsigned)(r - 1) << 32) | (u64)pack2bf(a, b));
    }
  }
}

// ---------------------------------------------------------------------------
__global__ __launch_bounds__(256) void logits_kernel(
    const float* __restrict__ wout, const float* __restrict__ bout,
    unsigned int* __restrict__ ws) {
  const float* h1f = reinterpret_cast<const float*>(ws + WS_H1F);
  float* lg = reinterpret_cast<float*>(ws + WS_LOG);
  const int lane = threadIdx.x & 63;
  const int wv = threadIdx.x >> 6;
  const int gw = blockIdx.x * 4 + wv;    // 1024 waves total
  const float4* h4 = reinterpret_cast<const float4*>(h1f);
  float4 h[4];
#pragma unroll
  for (int j = 0; j < 4; ++j) h[j] = h4[j * 64 + lane];
  for (int v = gw; v < VOCAB; v += 1024) {
    const float4* wr = reinterpret_cast<const float4*>(wout + (size_t)v * HID);
    float s = 0.f;
#pragma unroll
    for (int j = 0; j < 4; ++j) {
      float4 x = wr[j * 64 + lane];
      s += x.x * h[j].x + x.y * h[j].y + x.z * h[j].z + x.w * h[j].w;
    }
#pragma unroll
    for (int m = 32; m >= 1; m >>= 1) s += __shfl_xor(s, m, 64);
    if (lane == 0) lg[v] = s + bout[v];
  }
}

__global__ __launch_bounds__(1024) void lse_kernel(unsigned int* __restrict__ ws) {
  const float* lg = reinterpret_cast<const float*>(ws + WS_LOG);
  __shared__ float wred[16];
  __shared__ float mshare;
  const int tid = threadIdx.x;
  float m = -3.4e38f;
  for (int i = tid; i < VOCAB; i += 1024) m = fmaxf(m, lg[i]);
#pragma unroll
  for (int s = 32; s >= 1; s >>= 1) m = fmaxf(m, __shfl_xor(m, s, 64));
  if ((tid & 63) == 0) wred[tid >> 6] = m;
  __syncthreads();
  if (tid == 0) {
    float mm = wred[0];
    for (int i = 1; i < 16; ++i) mm = fmaxf(mm, wred[i]);
    mshare = mm;
  }
  __syncthreads();
  const float M = mshare;
  float a = 0.f;
  for (int i = tid; i < VOCAB; i += 1024) a += __expf(lg[i] - M);
#pragma unroll
  for (int s = 32; s >= 1; s >>= 1) a += __shfl_xor(a, s, 64);
  __syncthreads();
  if ((tid & 63) == 0) wred[tid >> 6] = a;
  __syncthreads();
  if (tid == 0) {
    float ss = 0.f;
    for (int i = 0; i < 16; ++i) ss += wred[i];
    reinterpret_cast<float*>(ws + WS_LSE)[0] = M + logf(ss);
  }
}

__global__ __launch_bounds__(256) void out_kernel(
    const unsigned int* __restrict__ ws, float* __restrict__ dout) {
  const float lse = reinterpret_cast<const float*>(ws + WS_LSE)[0];
  const float* lg = reinterpret_cast<const float*>(ws + WS_LOG);
  const int i = blockIdx.x * 256 + threadIdx.x;
  if (i < VOCAB) dout[i] = lg[i] - lse;
}

// ---------------------------------------------------------------------------
extern "C" void kernel_launch(void* const* d_in, const int* in_sizes, int n_in,
                              void* d_out, int out_size, void* d_ws, size_t ws_size,
                              hipStream_t stream) {
  const int*   tok  = (const int*)d_in[0];
  const float* h0in = (const float*)d_in[1];
  const float* c0in = (const float*)d_in[2];
  const float* emb  = (const float*)d_in[3];
  const float* wih0 = (const float*)d_in[4];
  const float* whh0 = (const float*)d_in[5];
  const float* bih0 = (const float*)d_in[6];
  const float* bhh0 = (const float*)d_in[7];
  const float* wih1 = (const float*)d_in[8];
  const float* whh1 = (const float*)d_in[9];
  const float* bih1 = (const float*)d_in[10];
  const float* bhh1 = (const float*)d_in[11];
  const float* wout = (const float*)d_in[12];
  const float* bout = (const float*)d_in[13];
  float* out = (float*)d_out;
  unsigned int* ws = (unsigned int*)d_ws;

  (void)in_sizes; (void)n_in; (void)out_size; (void)ws_size;

  (void)hipFuncSetAttribute((const void*)scan_kernel,
                            hipFuncAttributeMaxDynamicSharedMemorySize, SMEM_BYTES);

  reset_kernel<<<1, 512, 0, stream>>>(h0in, ws);
  scan_kernel<<<NBLK, TPB, SMEM_BYTES, stream>>>(
      tok, h0in, c0in, emb, wih0, whh0, bih0, bhh0,
      wih1, whh1, bih1, bhh1, out, ws);
  logits_kernel<<<256, 256, 0, stream>>>(wout, bout, ws);
  lse_kernel<<<1, 1024, 0, stream>>>(ws);
  out_kernel<<<(VOCAB + 255) / 256, 256, 0, stream>>>(ws, out);
}

// Round 10
// 12706.815 us; speedup vs baseline: 1.3525x; 1.2083x over previous
//
#include <hip/hip_runtime.h>

// ---------------------------------------------------------------------------
// 2-layer LSTM LM forward, MI355X persistent-kernel design, round 10.
// EXACT REVERT to the round-3 champion (12.72 ms measured) — the best point
// on a structure-invariant plateau (~3.1 us/round across R3/R7 structures).
//
//   round r (1..4097): layer0 computes step r, layer1 computes step r-1.
//   h travels as TAG-EMBEDDED u64 words ((round<<32)|bf16x2), all RELAXED
//   agent atomics -> zero fences in the steady-state loop, single global
//   hop per round. 2-deep parity ring; correctness from the happens-before
//   chain: consumer reads r-1 before publishing r, producer polls r before
//   overwriting with r+1.
// ---------------------------------------------------------------------------

#define T_SEQ 4096
#define HID   1024
#define EMBD  512
#define VOCAB 50257
#define NBLK  256
#define TPB   512
#define UB    4      // hidden units per block per layer
#define NSEG0 48     // (EMBD+HID)/32 k-segments, layer 0
#define NSEG1 64     // (HID+HID)/32  k-segments, layer 1

// workspace layout (32-bit word offsets)
#define WS_H0T 0       // u64[2][512]: (tag<<32)|bf16pair  (2048 u32 words)
#define WS_H1T 2048    // u64[2][512]
#define WS_H1F 4096    // float[1024] final h1
#define WS_LOG 5120    // float[50257] logits
#define WS_LSE 55377   // float[1]

// LDS layout (bytes)
#define OFF_W0 0                   // short8[NSEG0*64]  = 49152
#define OFF_W1 49152               // short8[NSEG1*64]  = 65536
#define OFF_V0 114688              // bf16[1536]  (x_t || h0_{r-1})
#define OFF_V1 117760              // bf16[2048]  (h0_{r-1} || h1_{r-2})
#define OFF_GP 121856              // float[7][16] gate partials
#define OFF_B0 122304              // float[16]
#define OFF_B1 122368              // float[16]
#define SMEM_BYTES 122432

typedef __attribute__((ext_vector_type(8))) short short8;
typedef __attribute__((ext_vector_type(4))) float f32x4;
typedef unsigned long long u64;

__device__ __forceinline__ unsigned short f2bf(float f) {
  unsigned int u = __float_as_uint(f);
  u += 0x7FFFu + ((u >> 16) & 1u);          // round-to-nearest-even
  return (unsigned short)(u >> 16);
}
__device__ __forceinline__ unsigned int pack2bf(float a, float b) {
  return (unsigned int)f2bf(a) | ((unsigned int)f2bf(b) << 16);
}
__device__ __forceinline__ float sigmoidf_(float x) {
  return 1.f / (1.f + __expf(-x));
}
__device__ __forceinline__ float tanhf_(float x) {
  return 1.f - 2.f / (__expf(2.f * x) + 1.f);
}

// 16 MFMA k-segments of the matvec. A = v replicated (any lane->k map
// cancels vs B); B = 16 gate-rows as columns, pre-swizzled in LDS.
// D: col = lane&15 = gate-row (HW-verified C/D layout).
template<int CNT>
__device__ __forceinline__ void mm_part(const short8* vf, const short8* wf,
                                        int s0, int lane, float* gout) {
  f32x4 a0 = {0.f, 0.f, 0.f, 0.f};
  f32x4 a1 = a0, a2 = a0, a3 = a0;
  const int grp = lane >> 4;
#pragma unroll
  for (int i = 0; i < CNT; ++i) {
    const int seg = s0 + i;
    short8 av = vf[seg * 4 + grp];
    short8 bv = wf[seg * 64 + lane];
    if ((i & 3) == 0)      a0 = __builtin_amdgcn_mfma_f32_16x16x32_bf16(av, bv, a0, 0, 0, 0);
    else if ((i & 3) == 1) a1 = __builtin_amdgcn_mfma_f32_16x16x32_bf16(av, bv, a1, 0, 0, 0);
    else if ((i & 3) == 2) a2 = __builtin_amdgcn_mfma_f32_16x16x32_bf16(av, bv, a2, 0, 0, 0);
    else                   a3 = __builtin_amdgcn_mfma_f32_16x16x32_bf16(av, bv, a3, 0, 0, 0);
  }
  f32x4 s = (a0 + a1) + (a2 + a3);
  if (lane < 16) gout[lane] = s[0];
}

// ---------------------------------------------------------------------------
__global__ __launch_bounds__(TPB, 1) void reset_kernel(
    const float* __restrict__ h0in, unsigned int* __restrict__ ws) {
  const int tid = threadIdx.x;
  u64* H0T = reinterpret_cast<u64*>(ws + WS_H0T);
  u64* H1T = reinterpret_cast<u64*>(ws + WS_H1T);
  // slot 0 <- initial hidden states, tag 0; slot 1 <- INVALID tag (kills
  // the cross-replay stale-tag race at rounds 4096/4097).
  H0T[tid] = (u64)pack2bf(h0in[2 * tid], h0in[2 * tid + 1]);
  H1T[tid] = (u64)pack2bf(h0in[HID + 2 * tid], h0in[HID + 2 * tid + 1]);
  H0T[512 + tid] = 0xFFFFFFFF00000000ULL;
  H1T[512 + tid] = 0xFFFFFFFF00000000ULL;
}

// ---------------------------------------------------------------------------
__global__ __launch_bounds__(TPB, 1) void scan_kernel(
    const int* __restrict__ tok,
    const float* __restrict__ h0in, const float* __restrict__ c0in,
    const float* __restrict__ emb,
    const float* __restrict__ wih0, const float* __restrict__ whh0,
    const float* __restrict__ bih0, const float* __restrict__ bhh0,
    const float* __restrict__ wih1, const float* __restrict__ whh1,
    const float* __restrict__ bih1, const float* __restrict__ bhh1,
    float* __restrict__ dout, unsigned int* __restrict__ ws) {
  extern __shared__ char smem[];
  short8* W0f = reinterpret_cast<short8*>(smem + OFF_W0);
  short8* W1f = reinterpret_cast<short8*>(smem + OFF_W1);
  unsigned int* v0w = reinterpret_cast<unsigned int*>(smem + OFF_V0);
  unsigned int* v1w = reinterpret_cast<unsigned int*>(smem + OFF_V1);
  const short8* v0f = reinterpret_cast<const short8*>(smem + OFF_V0);
  const short8* v1f = reinterpret_cast<const short8*>(smem + OFF_V1);
  float* gp  = reinterpret_cast<float*>(smem + OFF_GP);
  float* bs0 = reinterpret_cast<float*>(smem + OFF_B0);
  float* bs1 = reinterpret_cast<float*>(smem + OFF_B1);

  const int tid = threadIdx.x;
  const int bid = blockIdx.x;
  const int lane = tid & 63;
  const int w = tid >> 6;

  // ---- stage weights into LDS as pre-swizzled B-fragments (bf16) ----
  for (int slot = tid; slot < NSEG0 * 64; slot += TPB) {
    const int seg = slot >> 6, l = slot & 63;
    const int col = l & 15, grp = l >> 4;
    const int grow = (col >> 2) * HID + bid * UB + (col & 3);
    const int k0 = seg * 32 + grp * 8;
    const float* src = (k0 < EMBD) ? (wih0 + (size_t)grow * EMBD + k0)
                                   : (whh0 + (size_t)grow * HID + (k0 - EMBD));
    const float4* s4 = reinterpret_cast<const float4*>(src);
    float4 f0 = s4[0], f1 = s4[1];
    short8 pk;
    pk[0] = (short)f2bf(f0.x); pk[1] = (short)f2bf(f0.y);
    pk[2] = (short)f2bf(f0.z); pk[3] = (short)f2bf(f0.w);
    pk[4] = (short)f2bf(f1.x); pk[5] = (short)f2bf(f1.y);
    pk[6] = (short)f2bf(f1.z); pk[7] = (short)f2bf(f1.w);
    W0f[slot] = pk;
  }
  for (int slot = tid; slot < NSEG1 * 64; slot += TPB) {
    const int seg = slot >> 6, l = slot & 63;
    const int col = l & 15, grp = l >> 4;
    const int grow = (col >> 2) * HID + bid * UB + (col & 3);
    const int k0 = seg * 32 + grp * 8;
    const float* src = (k0 < HID) ? (wih1 + (size_t)grow * HID + k0)
                                  : (whh1 + (size_t)grow * HID + (k0 - HID));
    const float4* s4 = reinterpret_cast<const float4*>(src);
    float4 f0 = s4[0], f1 = s4[1];
    short8 pk;
    pk[0] = (short)f2bf(f0.x); pk[1] = (short)f2bf(f0.y);
    pk[2] = (short)f2bf(f0.z); pk[3] = (short)f2bf(f0.w);
    pk[4] = (short)f2bf(f1.x); pk[5] = (short)f2bf(f1.y);
    pk[6] = (short)f2bf(f1.z); pk[7] = (short)f2bf(f1.w);
    W1f[slot] = pk;
  }
  if (tid < 16) {
    const int grow = (tid >> 2) * HID + bid * UB + (tid & 3);
    bs0[tid] = bih0[grow] + bhh0[grow];
  } else if (tid < 32) {
    const int c = tid - 16;
    const int grow = (c >> 2) * HID + bid * UB + (c & 3);
    bs1[c] = bih1[grow] + bhh1[grow];
  }

  // cell state: wave0 lanes 0-3 hold layer0 c; wave3 lanes 0-3 hold layer1 c
  float cst = 0.f;
  if (w == 0 && lane < UB) cst = c0in[bid * UB + lane];
  if (w == 3 && lane < UB) cst = c0in[HID + bid * UB + lane];

  // prefetch x for round 1
  float xa = 0.f, xb = 0.f;
  if (tid < 256) {
    const float* xp = emb + (size_t)tok[0] * EMBD + tid * 2;
    xa = xp[0]; xb = xp[1];
  }

  u64* H0T = reinterpret_cast<u64*>(ws + WS_H0T);
  u64* H1T = reinterpret_cast<u64*>(ws + WS_H1T);

  for (int r = 1; r <= T_SEQ + 1; ++r) {
    // ---- write x_r to LDS from regs; issue x_{r+1} prefetch (drains during poll)
    if (tid < 256) {
      v0w[tid] = pack2bf(xa, xb);
      const int ridx = (r < T_SEQ) ? r : (T_SEQ - 1);
      const float* xp = emb + (size_t)tok[ridx] * EMBD + tid * 2;
      xa = xp[0]; xb = xp[1];
    }

    // ---- poll tag-embedded ring words (this thread's h0 word + h1 word) ----
    {
      const int p0 = (r - 1) & 1;          // h0_{r-1} lives in slot (r-1)&1
      const int p1 = r & 1;                // h1_{r-2} lives in slot (r-2)&1 == r&1
      const unsigned int tg0 = (unsigned int)(r - 1);
      const unsigned int tg1 = (unsigned int)(r - 2);
      const bool need1 = (r >= 2);
      u64 w0 = 0, w1 = 0;
      bool ok0 = false, ok1 = !need1;
      do {
        if (!ok0) {
          w0 = __hip_atomic_load(&H0T[p0 * 512 + tid], __ATOMIC_RELAXED,
                                 __HIP_MEMORY_SCOPE_AGENT);
          ok0 = ((unsigned int)(w0 >> 32) == tg0);
        }
        if (!ok1) {
          w1 = __hip_atomic_load(&H1T[p1 * 512 + tid], __ATOMIC_RELAXED,
                                 __HIP_MEMORY_SCOPE_AGENT);
          ok1 = ((unsigned int)(w1 >> 32) == tg1);
        }
      } while (!(ok0 && ok1));
      const unsigned int d0 = (unsigned int)w0;
      v0w[256 + tid] = d0;                 // v0[512..1535] = h0_{r-1}
      v1w[tid] = d0;                       // v1[0..1023]   = h0_{r-1}
      if (need1) v1w[512 + tid] = (unsigned int)w1;  // v1[1024..2047] = h1_{r-2}
    }
    __syncthreads();

    // ---- mm: waves 0-2 layer0 (48 segs), waves 3-6 layer1 (64 segs) ----
    if (w < 3) {
      if (r <= T_SEQ) mm_part<16>(v0f, W0f, w * 16, lane, gp + w * 16);
    } else if (w < 7) {
      if (r >= 2) mm_part<16>(v1f, W1f, (w - 3) * 16, lane, gp + w * 16);
    }
    __syncthreads();

    // ---- gates + tagged publish (wave0: layer0; wave3: layer1), no fence ----
    if (w == 0 && r <= T_SEQ) {
      float hv = 0.f;
      if (lane < UB) {
        const int u = lane;
        float gi = bs0[u], gf = bs0[4 + u], gg = bs0[8 + u], go = bs0[12 + u];
#pragma unroll
        for (int p = 0; p < 3; ++p) {
          gi += gp[p * 16 + u];      gf += gp[p * 16 + 4 + u];
          gg += gp[p * 16 + 8 + u];  go += gp[p * 16 + 12 + u];
        }
        const float c = sigmoidf_(gf) * cst + sigmoidf_(gi) * tanhf_(gg);
        cst = c;
        hv = sigmoidf_(go) * tanhf_(c);
        if (r == T_SEQ) {
          dout[VOCAB + bid * UB + u] = hv;              // h_n layer0
          dout[VOCAB + 2 * HID + bid * UB + u] = cst;   // c_n layer0
        }
      }
      const float a = __shfl(hv, 2 * (lane & 1));
      const float b = __shfl(hv, 2 * (lane & 1) + 1);
      if (lane < 2) {
        const u64 word = ((u64)(unsigned int)r << 32) | (u64)pack2bf(a, b);
        __hip_atomic_store(&H0T[(r & 1) * 512 + bid * 2 + lane], word,
                           __ATOMIC_RELAXED, __HIP_MEMORY_SCOPE_AGENT);
      }
    }
    if (w == 3 && r >= 2) {
      float hv = 0.f;
      if (lane < UB) {
        const int u = lane;
        float gi = bs1[u], gf = bs1[4 + u], gg = bs1[8 + u], go = bs1[12 + u];
#pragma unroll
        for (int p = 3; p < 7; ++p) {
          gi += gp[p * 16 + u];      gf += gp[p * 16 + 4 + u];
          gg += gp[p * 16 + 8 + u];  go += gp[p * 16 + 12 + u];
        }
        const float c = sigmoidf_(gf) * cst + sigmoidf_(gi) * tanhf_(gg);
        cst = c;
        hv = sigmoidf_(go) * tanhf_(c);
        if (r - 1 == T_SEQ) {
          float* h1f = reinterpret_cast<float*>(ws + WS_H1F);
          h1f[bid * UB + u] = hv;
          dout[VOCAB + HID + bid * UB + u] = hv;            // h_n layer1
          dout[VOCAB + 3 * HID + bid * UB + u] = cst;       // c_n layer1
        }
      }
      const float a = __shfl(hv, 2 * (lane & 1));
      const float b = __shfl(hv, 2 * (lane & 1) + 1);
      if (lane < 2) {
        const u64 word = ((u64)(unsigned int)(r - 1) << 32) | (u64)pack2bf(a, b);
        __hip_atomic_store(&H1T[((r - 1) & 1) * 512 + bid * 2 + lane], word,
                           __ATOMIC_RELAXED, __HIP_MEMORY_SCOPE_AGENT);
      }
    }
    // no trailing barrier: every consumer's next-round poll gates reuse,
    // and all LDS regions touched before sync(1) were last read pre-sync(2).
  }
}

// ---------------------------------------------------------------------------
__global__ __launch_bounds__(256) void logits_kernel(
    const float* __restrict__ wout, const float* __restrict__ bout,
    unsigned int* __restrict__ ws) {
  const float* h1f = reinterpret_cast<const float*>(ws + WS_H1F);
  float* lg = reinterpret_cast<float*>(ws + WS_LOG);
  const int lane = threadIdx.x & 63;
  const int wv = threadIdx.x >> 6;
  const int gw = blockIdx.x * 4 + wv;    // 1024 waves total
  const float4* h4 = reinterpret_cast<const float4*>(h1f);
  float4 h[4];
#pragma unroll
  for (int j = 0; j < 4; ++j) h[j] = h4[j * 64 + lane];
  for (int v = gw; v < VOCAB; v += 1024) {
    const float4* wr = reinterpret_cast<const float4*>(wout + (size_t)v * HID);
    float s = 0.f;
#pragma unroll
    for (int j = 0; j < 4; ++j) {
      float4 x = wr[j * 64 + lane];
      s += x.x * h[j].x + x.y * h[j].y + x.z * h[j].z + x.w * h[j].w;
    }
#pragma unroll
    for (int m = 32; m >= 1; m >>= 1) s += __shfl_xor(s, m, 64);
    if (lane == 0) lg[v] = s + bout[v];
  }
}

__global__ __launch_bounds__(1024) void lse_kernel(unsigned int* __restrict__ ws) {
  const float* lg = reinterpret_cast<const float*>(ws + WS_LOG);
  __shared__ float wred[16];
  __shared__ float mshare;
  const int tid = threadIdx.x;
  float m = -3.4e38f;
  for (int i = tid; i < VOCAB; i += 1024) m = fmaxf(m, lg[i]);
#pragma unroll
  for (int s = 32; s >= 1; s >>= 1) m = fmaxf(m, __shfl_xor(m, s, 64));
  if ((tid & 63) == 0) wred[tid >> 6] = m;
  __syncthreads();
  if (tid == 0) {
    float mm = wred[0];
    for (int i = 1; i < 16; ++i) mm = fmaxf(mm, wred[i]);
    mshare = mm;
  }
  __syncthreads();
  const float M = mshare;
  float a = 0.f;
  for (int i = tid; i < VOCAB; i += 1024) a += __expf(lg[i] - M);
#pragma unroll
  for (int s = 32; s >= 1; s >>= 1) a += __shfl_xor(a, s, 64);
  __syncthreads();
  if ((tid & 63) == 0) wred[tid >> 6] = a;
  __syncthreads();
  if (tid == 0) {
    float ss = 0.f;
    for (int i = 0; i < 16; ++i) ss += wred[i];
    reinterpret_cast<float*>(ws + WS_LSE)[0] = M + logf(ss);
  }
}

__global__ __launch_bounds__(256) void out_kernel(
    const unsigned int* __restrict__ ws, float* __restrict__ dout) {
  const float lse = reinterpret_cast<const float*>(ws + WS_LSE)[0];
  const float* lg = reinterpret_cast<const float*>(ws + WS_LOG);
  const int i = blockIdx.x * 256 + threadIdx.x;
  if (i < VOCAB) dout[i] = lg[i] - lse;
}

// ---------------------------------------------------------------------------
extern "C" void kernel_launch(void* const* d_in, const int* in_sizes, int n_in,
                              void* d_out, int out_size, void* d_ws, size_t ws_size,
                              hipStream_t stream) {
  const int*   tok  = (const int*)d_in[0];
  const float* h0in = (const float*)d_in[1];
  const float* c0in = (const float*)d_in[2];
  const float* emb  = (const float*)d_in[3];
  const float* wih0 = (const float*)d_in[4];
  const float* whh0 = (const float*)d_in[5];
  const float* bih0 = (const float*)d_in[6];
  const float* bhh0 = (const float*)d_in[7];
  const float* wih1 = (const float*)d_in[8];
  const float* whh1 = (const float*)d_in[9];
  const float* bih1 = (const float*)d_in[10];
  const float* bhh1 = (const float*)d_in[11];
  const float* wout = (const float*)d_in[12];
  const float* bout = (const float*)d_in[13];
  float* out = (float*)d_out;
  unsigned int* ws = (unsigned int*)d_ws;

  (void)in_sizes; (void)n_in; (void)out_size; (void)ws_size;

  (void)hipFuncSetAttribute((const void*)scan_kernel,
                            hipFuncAttributeMaxDynamicSharedMemorySize, SMEM_BYTES);

  reset_kernel<<<1, TPB, 0, stream>>>(h0in, ws);
  scan_kernel<<<NBLK, TPB, SMEM_BYTES, stream>>>(
      tok, h0in, c0in, emb, wih0, whh0, bih0, bhh0,
      wih1, whh1, bih1, bhh1, out, ws);
  logits_kernel<<<256, 256, 0, stream>>>(wout, bout, ws);
  lse_kernel<<<1, 1024, 0, stream>>>(ws);
  out_kernel<<<(VOCAB + 255) / 256, 256, 0, stream>>>(ws, out);
}